// Round 12
// baseline (31.917 us; speedup 1.0000x reference)
//
#include <hip/hip_runtime.h>
#include <cmath>

#ifndef M_PI
#define M_PI 3.14159265358979323846
#endif

constexpr int T_LEN    = 320000;
constexpr int ROW_VECS = T_LEN / 4;               // 80000 float4 per row
constexpr int B_ROWS   = 64;
constexpr int CHUNK    = 32;                      // samples per thread
constexpr int VPT      = CHUNK / 4;               // 8 float4 per chunk
constexpr int NCHUNK   = T_LEN / CHUNK;           // 10000 chunks per row
constexpr int BLK_CHUNKS = 128;                   // chunks per tile
constexpr int BLK_SPAN   = BLK_CHUNKS * CHUNK;    // 4096 samples per tile
constexpr int HALO       = 3;                     // halo chunks (state combine)
constexpr int HALO_VECS  = HALO * VPT;            // 24
constexpr int TILE_VECS  = HALO_VECS + BLK_CHUNKS * VPT;  // 1048 vecs = 16.8 KB
constexpr int NTILES_ROW = (NCHUNK + BLK_CHUNKS - 1) / BLK_CHUNKS;  // 79
constexpr int GRID_X     = 16;                    // 16x64 = 1024 blocks = 4/CU exactly
constexpr int NT_MAX     = (NTILES_ROW + GRID_X - 1) / GRID_X;      // 5 tiles/block

// Vector-granularity XOR swizzle (16B units). Involution, bijective within
// each aligned 8-vector (128B) group: linear LDS dest + inverse-swizzled
// global source + swizzled read (rule #21), coalescing preserved.
__device__ __forceinline__ int swzv(int V) { return V ^ ((V >> 3) & 7); }

typedef const __attribute__((address_space(1))) void glb_void;
typedef __attribute__((address_space(3))) void lds_void;

__global__ __launch_bounds__(256, 4) void biquad_pipe_kernel(
    const float* __restrict__ x, float* __restrict__ y,
    float b0, float b1, float b2, float a1, float a2,
    float q30, float p30, float q31, float p31) {
  const int bx   = blockIdx.x;
  const int row  = blockIdx.y;
  const int t    = threadIdx.x;
  const int wave = t >> 6;

  const int tile0  = bx * NT_MAX;
  const int ntiles = min(NT_MAX, NTILES_ROW - tile0);   // 5, or 4 for bx==15

  const float4* xr4 = reinterpret_cast<const float4*>(x + (size_t)row * T_LEN);
  float*        yr  = y + (size_t)row * T_LEN;

  __shared__ float4 buf[2][TILE_VECS];
  __shared__ float4 st[HALO + BLK_CHUNKS];   // (y1, y2, xlast1, xlast2)

  const int lane = t & 63;

  // Issue direct HBM->LDS staging for one tile (no waits here).
  auto stage = [&](int tileIdx, int pb) {
    const int S    = tileIdx * BLK_SPAN;
    const int ntot = HALO_VECS + min(BLK_CHUNKS, (T_LEN - S) / CHUNK) * VPT;
    const int gofs = S / 4 - HALO_VECS;
    for (int r = wave; r * 64 < ntot; r += 4) {
      int s  = r * 64 + lane;
      int gv = gofs + swzv(s);
      if (s < ntot && gv >= 0) {
        __builtin_amdgcn_global_load_lds((glb_void*)(xr4 + gv),
                                         (lds_void*)(&buf[pb][r * 64]), 16, 0, 0);
      }
    }
    // Row start: halo = zeros (exact rest state). Only ever true in prologue.
    if (tileIdx == 0 && t < HALO_VECS) buf[pb][t] = make_float4(0.f, 0.f, 0.f, 0.f);
  };

  auto stepf = [&](float xn, float& X1, float& X2, float& Y1, float& Y2) -> float {
    float tt = fmaf(b2, X2, fmaf(b1, X1, b0 * xn));
    float u  = fmaf(-a2, Y2, tt);
    float yn = fmaf(-a1, Y1, u);
    X2 = X1; X1 = xn;
    Y2 = Y1; Y1 = yn;
    return yn;
  };

  // ---- Prologue: stage first tile; full drain wanted here.
  stage(tile0, 0);
  __syncthreads();   // vmcnt(0)+lgkmcnt(0) drain: tile0 (and halo zero-fill) ready

  int pb = 0;
  for (int i = 0; i < ntiles; ++i) {
    const int tileIdx = tile0 + i;
    const int S       = tileIdx * BLK_SPAN;
    const int nchunks = min(BLK_CHUNKS, (T_LEN - S) / CHUNK);  // 128 (16 on tile 78)
    const int nvecs   = nchunks * VPT;
    const float4* cur = buf[pb];
    float4*       curw = buf[pb];

    // ---- Issue next tile's DMA early (flies under compute + store).
    if (i + 1 < ntiles) stage(tileIdx + 1, pb ^ 1);

    // ---- Phase 2a: halo chunks' zero-IC end states (threads 0..2).
    if (t < HALO) {
      float4 h[VPT];
#pragma unroll
      for (int k = 0; k < VPT; ++k) h[k] = cur[swzv(t * VPT + k)];
      float hxl1 = h[VPT - 1].w, hxl2 = h[VPT - 1].z;
      float hx1 = 0.f, hx2 = 0.f, hy1 = 0.f, hy2 = 0.f;
#pragma unroll
      for (int k = 0; k < VPT; ++k) {
        stepf(h[k].x, hx1, hx2, hy1, hy2); stepf(h[k].y, hx1, hx2, hy1, hy2);
        stepf(h[k].z, hx1, hx2, hy1, hy2); stepf(h[k].w, hx1, hx2, hy1, hy2);
      }
      st[t] = make_float4(hy1, hy2, hxl1, hxl2);
    }

    // ---- Phase 2b: zero-IC pass over own chunk.
    const bool active = (t < nchunks);
    float4 m[VPT];
    const int vb = HALO_VECS + t * VPT;
    if (active) {
#pragma unroll
      for (int k = 0; k < VPT; ++k) m[k] = cur[swzv(vb + k)];
      float xl1 = m[VPT - 1].w, xl2 = m[VPT - 1].z;
      float x1 = 0.f, x2 = 0.f, y1 = 0.f, y2 = 0.f;
#pragma unroll
      for (int k = 0; k < VPT; ++k) {
        float4 v = m[k];
        m[k] = make_float4(stepf(v.x, x1, x2, y1, y2), stepf(v.y, x1, x2, y1, y2),
                           stepf(v.z, x1, x2, y1, y2), stepf(v.w, x1, x2, y1, y2));
      }
      st[HALO + t] = make_float4(y1, y2, xl1, xl2);
    }
    // Raw barrier: LDS-visibility only. MUST NOT drain vmcnt (prefetch in flight).
    asm volatile("s_waitcnt lgkmcnt(0)" ::: "memory");
    __builtin_amdgcn_s_barrier();
    __builtin_amdgcn_sched_barrier(0);

    // ---- Phase 3: 2-level state combine + correction, writeback to cur.
    if (active) {
      const int ii = HALO + t;
      float4 sm3 = st[ii - 3], sm2 = st[ii - 2], sm1 = st[ii - 1];
      float cA0 = fmaf(b1, sm3.z, fmaf(b2, sm3.w, fmaf(-a1, sm3.x, -a2 * sm3.y)));
      float cA1 = fmaf(-a1, cA0, fmaf(b2, sm3.z, -a2 * sm3.x));
      float yA1 = fmaf(q31, cA0, fmaf(p31, cA1, sm2.x));
      float yA2 = fmaf(q30, cA0, fmaf(p30, cA1, sm2.y));
      float cB0 = fmaf(b1, sm2.z, fmaf(b2, sm2.w, fmaf(-a1, yA1, -a2 * yA2)));
      float cB1 = fmaf(-a1, cB0, fmaf(b2, sm2.z, -a2 * yA1));
      float yB1 = fmaf(q31, cB0, fmaf(p31, cB1, sm1.x));
      float yB2 = fmaf(q30, cB0, fmaf(p30, cB1, sm1.y));
      float c0 = fmaf(b1, sm1.z, fmaf(b2, sm1.w, fmaf(-a1, yB1, -a2 * yB2)));
      float c1 = fmaf(-a1, c0, fmaf(b2, sm1.z, -a2 * yB1));
      float cm2, cm1;
      {
        m[0].x += c0; m[0].y += c1;
        float c2 = fmaf(-a1, c1, -a2 * c0); m[0].z += c2;
        float c3 = fmaf(-a1, c2, -a2 * c1); m[0].w += c3;
        cm2 = c2; cm1 = c3;
      }
#pragma unroll
      for (int k = 1; k < VPT; ++k) {
        float ca = fmaf(-a1, cm1, -a2 * cm2); m[k].x += ca;
        float cb = fmaf(-a1, ca, -a2 * cm1);  m[k].y += cb;
        float cc = fmaf(-a1, cb, -a2 * ca);   m[k].z += cc;
        float cd = fmaf(-a1, cc, -a2 * cb);   m[k].w += cd;
        cm2 = cc; cm1 = cd;
      }
#pragma unroll
      for (int k = 0; k < VPT; ++k) curw[swzv(vb + k)] = m[k];
    }
    asm volatile("s_waitcnt lgkmcnt(0)" ::: "memory");
    __builtin_amdgcn_s_barrier();
    __builtin_amdgcn_sched_barrier(0);

    // ---- Phase 4: coalesced store via swizzled ds_read_b128.
    {
      float4* dst = reinterpret_cast<float4*>(yr + S);
#pragma unroll
      for (int j = 0; j < 4; ++j) {
        int v = t + 256 * j;
        if (v < nvecs) dst[v] = cur[swzv(HALO_VECS + v)];
      }
    }

    // ---- Tile-ready wait for the prefetched tile: counted vmcnt.
    // Outstanding (FIFO): loads(i+1) [older] then this tile's 4 stores
    // [newest]. vmcnt(4) drains the loads, leaves the stores in flight.
    if (i + 1 < ntiles) {
      asm volatile("s_waitcnt vmcnt(4)" ::: "memory");
      __builtin_amdgcn_s_barrier();
      __builtin_amdgcn_sched_barrier(0);
    }
    pb ^= 1;
  }
}

extern "C" void kernel_launch(void* const* d_in, const int* in_sizes, int n_in,
                              void* d_out, int out_size, void* d_ws, size_t ws_size,
                              hipStream_t stream) {
  const float* x = (const float*)d_in[0];
  float*       y = (float*)d_out;

  const double sample_rate = 16000.0, cutoff = 7500.0, Q = 0.707;
  double w0    = 2.0 * M_PI * cutoff / sample_rate;
  double alpha = sin(w0) / (2.0 * Q);
  double cw    = cos(w0);
  double a0    = 1.0 + alpha;
  double b0d = ((1.0 - cw) * 0.5) / a0;
  double b1d = (1.0 - cw) / a0;
  double a1d = (-2.0 * cw) / a0;
  double a2d = (1.0 - alpha) / a0;

  // Homogeneous propagators: c_n = q_n*c_0 + p_n*c_1.
  double qm2 = 1.0, pm2 = 0.0, qm1 = 0.0, pm1 = 1.0;
  double q30 = 0, p30 = 0, q31 = 0, p31 = 0;
  for (int n = 2; n < CHUNK; ++n) {
    double qn = -a1d * qm1 - a2d * qm2;
    double pn = -a1d * pm1 - a2d * pm2;
    qm2 = qm1; pm2 = pm1; qm1 = qn; pm1 = pn;
    if (n == 30) { q30 = qn; p30 = pn; }
    if (n == 31) { q31 = qn; p31 = pn; }
  }

  dim3 block(256);
  dim3 grid(GRID_X, B_ROWS);   // 16 x 64 = 1024 blocks = 4/CU exactly
  hipLaunchKernelGGL(biquad_pipe_kernel, grid, block, 0, stream,
                     x, y, (float)b0d, (float)b1d, (float)b0d, (float)a1d, (float)a2d,
                     (float)q30, (float)p30, (float)q31, (float)p31);
}

// Round 13
// 30.384 us; speedup vs baseline: 1.0505x; 1.0505x over previous
//
#include <hip/hip_runtime.h>
#include <cmath>

#ifndef M_PI
#define M_PI 3.14159265358979323846
#endif

constexpr int T_LEN    = 320000;
constexpr int ROW_VECS = T_LEN / 4;               // 80000 float4 per row
constexpr int B_ROWS   = 64;
constexpr int CHUNK    = 32;                      // samples per thread
constexpr int VPT      = CHUNK / 4;               // 8 float4 per chunk
constexpr int NCHUNK   = T_LEN / CHUNK;           // 10000 chunks per row
constexpr int BLK_CHUNKS = 128;                   // chunks per block
constexpr int BLK_SPAN   = BLK_CHUNKS * CHUNK;    // 4096 samples per block
constexpr int HALO       = 3;                     // halo chunks (state combine)
constexpr int HALO_VECS  = HALO * VPT;            // 24
constexpr int TILE_VECS  = HALO_VECS + BLK_CHUNKS * VPT;  // 1048 vecs = 16.8 KB

// Vector-granularity XOR swizzle (16B units). INVOLUTION, bijective within
// each aligned 8-vector (128B) group -> pre-swizzling the global source
// address keeps wave loads inside the same 128B segments (coalesced), per
// rule #21: linear LDS dest + inverse-swz source + swz on read.
__device__ __forceinline__ int swzv(int V) { return V ^ ((V >> 3) & 7); }

typedef const __attribute__((address_space(1))) void glb_void;
typedef __attribute__((address_space(3))) void lds_void;

__global__ __launch_bounds__(256, 8) void biquad_gll_kernel(
    const float* __restrict__ x, float* __restrict__ y,
    float b0, float b1, float b2, float a1, float a2,
    float q30, float p30, float q31, float p31) {
  const int b    = blockIdx.x;
  const int row  = blockIdx.y;
  const int t    = threadIdx.x;
  const int wave = t >> 6;
  const int lane = t & 63;

  const int S       = b * BLK_SPAN;
  const int nchunks = min(BLK_CHUNKS, (T_LEN - S) / CHUNK);  // 128, or 16 (tail)
  const int nvecs   = nchunks * VPT;
  const int ntot    = HALO_VECS + nvecs;

  const float4* xr4 = reinterpret_cast<const float4*>(x + (size_t)row * T_LEN);
  float*        yr  = y + (size_t)row * T_LEN;

  __shared__ float4 tile[TILE_VECS];
  __shared__ float4 st[HALO + BLK_CHUNKS];   // (y1, y2, xlast1, xlast2)

  // ---- Phase 1: direct HBM->LDS staging. LDS slot s receives logical vec
  // swzv(s) (involution), i.e. global addr is pre-inverse-swizzled per lane;
  // LDS dest is the wave-uniform base + lane*16 that the HW requires.
  {
    const int gofs = S / 4 - HALO_VECS;   // global vec offset of slot 0
    for (int r = wave; r * 64 < ntot; r += 4) {
      int s  = r * 64 + lane;
      int gv = gofs + swzv(s);
      if (s < ntot && gv >= 0) {
        __builtin_amdgcn_global_load_lds((glb_void*)(xr4 + gv),
                                         (lds_void*)(tile + r * 64), 16, 0, 0);
      }
    }
    // Block 0: halo = zeros (exact rest state). Slots [0,24) hold the halo.
    if (b == 0 && t < HALO_VECS) tile[t] = make_float4(0.f, 0.f, 0.f, 0.f);
  }
  __syncthreads();   // drains vmcnt (gload_lds) + lgkmcnt (zero-fill)

  auto stepf = [&](float xn, float& X1, float& X2, float& Y1, float& Y2) -> float {
    float tt = fmaf(b2, X2, fmaf(b1, X1, b0 * xn));
    float u  = fmaf(-a2, Y2, tt);
    float yn = fmaf(-a1, Y1, u);
    X2 = X1; X1 = xn;
    Y2 = Y1; Y1 = yn;
    return yn;
  };

  // ---- Phase 2a: halo chunks' zero-IC end states (threads 0..2 only).
  if (t < HALO) {
    float4 h[VPT];
#pragma unroll
    for (int k = 0; k < VPT; ++k) h[k] = tile[swzv(t * VPT + k)];
    float hxl1 = h[VPT - 1].w, hxl2 = h[VPT - 1].z;
    float hx1 = 0.f, hx2 = 0.f, hy1 = 0.f, hy2 = 0.f;
#pragma unroll
    for (int k = 0; k < VPT; ++k) {
      stepf(h[k].x, hx1, hx2, hy1, hy2); stepf(h[k].y, hx1, hx2, hy1, hy2);
      stepf(h[k].z, hx1, hx2, hy1, hy2); stepf(h[k].w, hx1, hx2, hy1, hy2);
    }
    st[t] = make_float4(hy1, hy2, hxl1, hxl2);
  }

  // ---- Phase 2b: zero-IC pass over own chunk.
  const bool active = (t < nchunks);
  float4 m[VPT];
  const int vb = HALO_VECS + t * VPT;
  if (active) {
#pragma unroll
    for (int k = 0; k < VPT; ++k) m[k] = tile[swzv(vb + k)];
    float xl1 = m[VPT - 1].w, xl2 = m[VPT - 1].z;
    float x1 = 0.f, x2 = 0.f, y1 = 0.f, y2 = 0.f;
#pragma unroll
    for (int k = 0; k < VPT; ++k) {
      float4 v = m[k];
      m[k] = make_float4(stepf(v.x, x1, x2, y1, y2), stepf(v.y, x1, x2, y1, y2),
                         stepf(v.z, x1, x2, y1, y2), stepf(v.w, x1, x2, y1, y2));
    }
    st[HALO + t] = make_float4(y1, y2, xl1, xl2);
  }
  __syncthreads();

  // ---- Phase 3: 2-level state combine + correction chain (verified math).
  if (active) {
    const int i = HALO + t;
    float4 sm3 = st[i - 3], sm2 = st[i - 2], sm1 = st[i - 1];
    // Level A: corrected end-state of chunk t-2 (seeds from t-3, raw z).
    float cA0 = fmaf(b1, sm3.z, fmaf(b2, sm3.w, fmaf(-a1, sm3.x, -a2 * sm3.y)));
    float cA1 = fmaf(-a1, cA0, fmaf(b2, sm3.z, -a2 * sm3.x));
    float yA1 = fmaf(q31, cA0, fmaf(p31, cA1, sm2.x));
    float yA2 = fmaf(q30, cA0, fmaf(p30, cA1, sm2.y));
    // Level B: corrected end-state of chunk t-1.
    float cB0 = fmaf(b1, sm2.z, fmaf(b2, sm2.w, fmaf(-a1, yA1, -a2 * yA2)));
    float cB1 = fmaf(-a1, cB0, fmaf(b2, sm2.z, -a2 * yA1));
    float yB1 = fmaf(q31, cB0, fmaf(p31, cB1, sm1.x));
    float yB2 = fmaf(q30, cB0, fmaf(p30, cB1, sm1.y));
    // Final seeds for own chunk.
    float c0 = fmaf(b1, sm1.z, fmaf(b2, sm1.w, fmaf(-a1, yB1, -a2 * yB2)));
    float c1 = fmaf(-a1, c0, fmaf(b2, sm1.z, -a2 * yB1));
    // Apply correction chain (register-only).
    float cm2, cm1;
    {
      m[0].x += c0; m[0].y += c1;
      float c2 = fmaf(-a1, c1, -a2 * c0); m[0].z += c2;
      float c3 = fmaf(-a1, c2, -a2 * c1); m[0].w += c3;
      cm2 = c2; cm1 = c3;
    }
#pragma unroll
    for (int k = 1; k < VPT; ++k) {
      float ca = fmaf(-a1, cm1, -a2 * cm2); m[k].x += ca;
      float cb = fmaf(-a1, ca, -a2 * cm1);  m[k].y += cb;
      float cc = fmaf(-a1, cb, -a2 * ca);   m[k].z += cc;
      float cd = fmaf(-a1, cc, -a2 * cb);   m[k].w += cd;
      cm2 = cc; cm1 = cd;
    }
    // Own region is only read by this thread in phase 2 -> safe to overwrite.
#pragma unroll
    for (int k = 0; k < VPT; ++k) tile[swzv(vb + k)] = m[k];
  }
  __syncthreads();

  // ---- Phase 4: coalesced float4 store via swizzled ds_read_b128.
  {
    float4* dst = reinterpret_cast<float4*>(yr + S);
#pragma unroll
    for (int j = 0; j < 4; ++j) {
      int i = t + 256 * j;
      if (i < nvecs) dst[i] = tile[swzv(HALO_VECS + i)];
    }
  }
}

extern "C" void kernel_launch(void* const* d_in, const int* in_sizes, int n_in,
                              void* d_out, int out_size, void* d_ws, size_t ws_size,
                              hipStream_t stream) {
  const float* x = (const float*)d_in[0];
  float*       y = (float*)d_out;

  const double sample_rate = 16000.0, cutoff = 7500.0, Q = 0.707;
  double w0    = 2.0 * M_PI * cutoff / sample_rate;
  double alpha = sin(w0) / (2.0 * Q);
  double cw    = cos(w0);
  double a0    = 1.0 + alpha;
  double b0d = ((1.0 - cw) * 0.5) / a0;
  double b1d = (1.0 - cw) / a0;
  double a1d = (-2.0 * cw) / a0;
  double a2d = (1.0 - alpha) / a0;

  // Homogeneous propagators: c_n = q_n*c_0 + p_n*c_1.
  double qm2 = 1.0, pm2 = 0.0, qm1 = 0.0, pm1 = 1.0;
  double q30 = 0, p30 = 0, q31 = 0, p31 = 0;
  for (int n = 2; n < CHUNK; ++n) {
    double qn = -a1d * qm1 - a2d * qm2;
    double pn = -a1d * pm1 - a2d * pm2;
    qm2 = qm1; pm2 = pm1; qm1 = qn; pm1 = pn;
    if (n == 30) { q30 = qn; p30 = pn; }
    if (n == 31) { q31 = qn; p31 = pn; }
  }

  dim3 block(256);
  dim3 grid((NCHUNK + BLK_CHUNKS - 1) / BLK_CHUNKS, B_ROWS);  // 79 x 64
  hipLaunchKernelGGL(biquad_gll_kernel, grid, block, 0, stream,
                     x, y, (float)b0d, (float)b1d, (float)b0d, (float)a1d, (float)a2d,
                     (float)q30, (float)p30, (float)q31, (float)p31);
}